// Round 1
// baseline (78.806 us; speedup 1.0000x reference)
//
#include <hip/hip_runtime.h>
#include <math.h>

#define BATCH 262144
#define N 8
#define BLK 64
#define RPT 2                    // rows per thread (ILP: two independent pipelines)
#define NTHR (BATCH / RPT)       // 131072 threads
#define NBLK (NTHR / BLK)        // 2048 single-wave blocks
#define NCMP 28                  // odd-even network on 8 elems

// Comparator schedule + per-row support masks (which P-row entries can be
// nonzero BEFORE comparator k). P starts as I, so early comparators touch
// known-zeros -> skip (0 ops) or half-blend (2 ops) instead of full (3 ops).
struct Net { int a[NCMP]; unsigned sup[N][NCMP]; };
constexpr Net make_net() {
    Net n{};
    int k = 0;
    for (int L = 0; L < N; ++L)
        for (int a = (L & 1); a < N - 1; a += 2)
            n.a[k++] = a;
    for (int r = 0; r < N; ++r) {
        unsigned s = 1u << r;
        for (int q = 0; q < NCMP; ++q) {
            n.sup[r][q] = s;
            unsigned m = 3u << n.a[q];
            if (s & m) s |= m;
        }
    }
    return n;
}
constexpr Net NET = make_net();

// alpha(z) = 0.5 + atan(z)/pi. Deg-5 minimax atan on [0,1] (|err|~6e-5,
// relative error preserved through the rcp arg-reduction).
__device__ __forceinline__ float cauchy_alpha(float z10) {
    float az  = __builtin_fabsf(z10);
    bool  big = az > 1.0f;
    float inv = __builtin_amdgcn_rcpf(az);
    float t   = big ? inv : az;
    float t2  = t * t;
    float p   = 0.1417796f;
    p = __builtin_fmaf(p, t2, -0.3258092f);
    p = __builtin_fmaf(p, t2, 0.9992150f);
    float at = p * t;
    float r  = big ? (1.5707963267948966f - at) : at;
    float sr = __builtin_copysignf(r, z10);
    return __builtin_fmaf(sr, 0.31830988618379067f, 0.5f);
}

// Two rows per thread, interleaved per comparator: two independent dep chains
// (alpha chain is ~9 deep incl. v_rcp) give the scheduler ILP=2, compensating
// the occupancy drop from 4 -> 2 waves/SIMD (grid supplies only 2048 waves).
// VGPR ~190 (two P tiles live) -> __launch_bounds__(64,2) caps at 256, no spill.
__global__ __launch_bounds__(BLK, 2) void diffsort_loss_kernel(
    const float* __restrict__ pred,
    const float* __restrict__ labels,
    const float* __restrict__ rank_ema,
    float* __restrict__ partial)
{
    const int tid = blockIdx.x * BLK + threadIdx.x;

    // tiny uniform ema table -> LDS
    __shared__ float ema[N];
    if (threadIdx.x < N) ema[threadIdx.x] = rank_ema[threadIdx.x];
    __syncthreads();

    // ---- vectorized row loads (both rows issued up front, one vmcnt wait) ----
    float lab[RPT][N], prd[RPT][N];
#pragma unroll
    for (int r = 0; r < RPT; ++r) {
        const size_t row = (size_t)tid + (size_t)(r * NTHR);
        const float4* lp = (const float4*)(labels + row * N);
        const float4* pp = (const float4*)(pred   + row * N);
        const float4 l0 = lp[0], l1 = lp[1];
        const float4 p0 = pp[0], p1 = pp[1];
        lab[r][0]=l0.x; lab[r][1]=l0.y; lab[r][2]=l0.z; lab[r][3]=l0.w;
        lab[r][4]=l1.x; lab[r][5]=l1.y; lab[r][6]=l1.z; lab[r][7]=l1.w;
        prd[r][0]=p0.x; prd[r][1]=p0.y; prd[r][2]=p0.z; prd[r][3]=p0.w;
        prd[r][4]=p1.x; prd[r][5]=p1.y; prd[r][6]=p1.z; prd[r][7]=p1.w;
    }

    // ---- rank_true via pairwise comparisons (stable argsort of -labels) ----
    int rt[RPT][N];
#pragma unroll
    for (int r = 0; r < RPT; ++r) {
#pragma unroll
        for (int i = 0; i < N; ++i) rt[r][i] = 0;
#pragma unroll
        for (int i = 0; i < N; ++i)
#pragma unroll
            for (int j = i + 1; j < N; ++j) {
                unsigned c = lab[r][j] > lab[r][i];
                rt[r][i] += c;
                rt[r][j] += 1u - c;
            }
    }

    // ---- x = rank_ema[rt] - pred  (= -shifted) ----
    float x[RPT][N];
#pragma unroll
    for (int r = 0; r < RPT; ++r)
#pragma unroll
        for (int i = 0; i < N; ++i)
            x[r][i] = ema[rt[r][i]] - prd[r][i];

    // ---- odd-even network: x and full P updated together per comparator ----
    float P[RPT][N][N];
#pragma unroll
    for (int r = 0; r < RPT; ++r)
#pragma unroll
        for (int i = 0; i < N; ++i)
#pragma unroll
            for (int j = 0; j < N; ++j)
                P[r][i][j] = (i == j) ? 1.0f : 0.0f;

#pragma unroll
    for (int k = 0; k < NCMP; ++k) {
        const int ia = NET.a[k], ib = ia + 1;
#pragma unroll
        for (int r = 0; r < RPT; ++r) {
            const float a = x[r][ia], b = x[r][ib];
            const float z = b - a;
            const float alpha = cauchy_alpha(10.0f * z);
            x[r][ia] = __builtin_fmaf(-alpha, z, b);  // alpha*a + (1-alpha)*b
            x[r][ib] = __builtin_fmaf( alpha, z, a);  // (1-alpha)*a + alpha*b
#pragma unroll
            for (int i = 0; i < N; ++i) {
                const bool na = (NET.sup[i][k] >> ia) & 1u;   // compile-time
                const bool nb = (NET.sup[i][k] >> ib) & 1u;   // compile-time
                if (na && nb) {
                    const float ca = P[r][i][ia], cb = P[r][i][ib];
                    const float d = ca - cb;
                    P[r][i][ia] = __builtin_fmaf( alpha, d, cb);
                    P[r][i][ib] = __builtin_fmaf(-alpha, d, ca);
                } else if (na) {
                    const float ca = P[r][i][ia];
                    P[r][i][ia] = alpha * ca;
                    P[r][i][ib] = __builtin_fmaf(-alpha, ca, ca);
                } else if (nb) {
                    const float cb = P[r][i][ib];
                    P[r][i][ia] = __builtin_fmaf(-alpha, cb, cb);
                    P[r][i][ib] = alpha * cb;
                } // else both zero: skip
            }
        }
    }

    // ---- loss: row i one-hot at col rt[i]:
    //      log( p[h] * prod_{j!=h}(1-p[j]) ), one log2 per row; scale by ln2
    //      once at the end (saves a mul per row). ----
    float s2 = 0.0f;
#pragma unroll
    for (int r = 0; r < RPT; ++r)
#pragma unroll
        for (int i = 0; i < N; ++i) {
            const int hj = rt[r][i];
            float arg = 1.0f;
#pragma unroll
            for (int j = 0; j < N; ++j) {
                const float pj = P[r][i][j];
                arg *= (hj == j) ? pj : (1.0f - pj);
            }
            s2 += __log2f(fmaxf(arg, 1e-37f));
        }
    float s = s2 * 0.69314718055994531f;

    // ---- wave(64) shuffle reduce -> one partial per wave-block ----
#pragma unroll
    for (int off = 32; off > 0; off >>= 1)
        s += __shfl_down(s, off);
    if (threadIdx.x == 0) partial[blockIdx.x] = s;
}

__global__ __launch_bounds__(256) void reduce_partials(
    const float* __restrict__ partial, float* __restrict__ out)
{
    float s = 0.0f;
#pragma unroll
    for (int k = 0; k < NBLK / 256; ++k)
        s += partial[threadIdx.x + k * 256];
#pragma unroll
    for (int off = 32; off > 0; off >>= 1)
        s += __shfl_down(s, off);

    __shared__ float wsum[4];
    const int lane = threadIdx.x & 63;
    const int wid  = threadIdx.x >> 6;
    if (lane == 0) wsum[wid] = s;
    __syncthreads();
    if (threadIdx.x == 0) {
        const float tot = wsum[0] + wsum[1] + wsum[2] + wsum[3];
        // loss = -sum / (B * n * n) = -sum / 16777216
        out[0] = -tot * (1.0f / 16777216.0f);
    }
}

extern "C" void kernel_launch(void* const* d_in, const int* in_sizes, int n_in,
                              void* d_out, int out_size, void* d_ws, size_t ws_size,
                              hipStream_t stream)
{
    const float* pred     = (const float*)d_in[0];
    const float* labels   = (const float*)d_in[1];
    const float* rank_ema = (const float*)d_in[2];
    float* out     = (float*)d_out;
    float* partial = (float*)d_ws;   // NBLK*4 = 8 KiB scratch

    diffsort_loss_kernel<<<NBLK, BLK, 0, stream>>>(pred, labels, rank_ema, partial);
    reduce_partials<<<1, 256, 0, stream>>>(partial, out);
}